// Round 13
// baseline (167.055 us; speedup 1.0000x reference)
//
#include <hip/hip_runtime.h>
#include <math.h>

namespace {
constexpr int N_   = 50000;
constexpr int E_   = 800000;
constexpr int EP_  = E_ + N_;   // edges + self loops = 850000
constexpr float SLOPE = 0.2f;

constexpr int NB_    = (N_ + 127) / 128;          // 391 coarse buckets (dst>>7)
constexpr int CHUNK_ = 8192;                      // edges per scatter block
constexpr int NBLKA_ = (EP_ + CHUNK_ - 1) / CHUNK_; // 104
constexpr int CAPB_  = 4096;                      // LDS capacity per bucket
constexpr int NBLKG_ = (N_ + 63) / 64;            // 782 gemm blocks (64 rows)

// workspace layout (bytes)
constexpr size_t OFF_H1  = 0;                                    // [N][128] bf16
constexpr size_t OFF_Y1  = OFF_H1  + (size_t)N_ * 128 * 2;       // [N][128] bf16
constexpr size_t OFF_H2  = OFF_Y1  + (size_t)N_ * 128 * 2;       // [N][64] bf16
constexpr size_t OFF_AS1 = OFF_H2  + (size_t)N_ * 64 * 2;        // [N][4]
constexpr size_t OFF_AD1 = OFF_AS1 + (size_t)N_ * 4 * 4;         // [N][4]
constexpr size_t OFF_AS2 = OFF_AD1 + (size_t)N_ * 4 * 4;         // [N]
constexpr size_t OFF_AD2 = OFF_AS2 + (size_t)N_ * 4;             // [N]
constexpr size_t OFF_ROW = OFF_AD2 + (size_t)N_ * 4;             // [N+1] int
constexpr size_t OFF_GC  = OFF_ROW + (((size_t)(N_ + 1) * 4 + 15) & ~(size_t)15); // [NB] int
constexpr size_t OFF_GO  = OFF_GC  + (((size_t)NB_ * 4 + 15) & ~(size_t)15);      // [NB+1] int
constexpr size_t OFF_GU  = OFF_GO  + (((size_t)(NB_ + 1) * 4 + 15) & ~(size_t)15);// [NB] int
constexpr size_t OFF_EB1 = OFF_GU  + (((size_t)NB_ * 4 + 15) & ~(size_t)15);      // [EP] u32 (src<<16|dst)
constexpr size_t OFF_EB  = OFF_EB1 + (size_t)EP_ * 4;            // [EP] int (src, dst-sorted)
}

typedef __attribute__((ext_vector_type(8))) short short8;
typedef __attribute__((ext_vector_type(4))) float f32x4;

__device__ __forceinline__ unsigned short f2bf(float x) {   // RNE
  unsigned u = __float_as_uint(x);
  return (unsigned short)((u + 0x7FFFu + ((u >> 16) & 1u)) >> 16);
}
__device__ __forceinline__ unsigned pack2bf(float a, float b) {
  return (unsigned)f2bf(a) | ((unsigned)f2bf(b) << 16);
}
__device__ __forceinline__ float bf_lo(unsigned u) { return __uint_as_float(u << 16); }
__device__ __forceinline__ float bf_hi(unsigned u) { return __uint_as_float(u & 0xFFFF0000u); }

// ------- Fused GEMM1 (MFMA bf16) + edge histogram -------------------------
__global__ __launch_bounds__(256, 3) void k_g1h(const float* __restrict__ x,
    const float* __restrict__ W, const float* __restrict__ av_s,
    const float* __restrict__ av_d, unsigned short* __restrict__ hbf,
    float* __restrict__ a_s, float* __restrict__ a_d,
    const int* __restrict__ ei, int* __restrict__ gcount)
{
  __shared__ __align__(16) char smem[52224];
  const int t = threadIdx.x;
  if (blockIdx.x >= NBLKG_) {
    int* nh = (int*)smem;
    for (int j = t; j < NB_; j += 256) nh[j] = 0;
    __syncthreads();
    const int beg = (blockIdx.x - NBLKG_) * CHUNK_;
    const int end = min(beg + CHUNK_, EP_);
    for (int i = beg + t; i < end; i += 256) {
      const int dd = (i < E_) ? ei[E_ + i] : (i - E_);
      atomicAdd(&nh[dd >> 7], 1);
    }
    __syncthreads();
    for (int j = t; j < NB_; j += 256)
      if (nh[j]) atomicAdd(&gcount[j], nh[j]);
    return;
  }
  unsigned short* xs = (unsigned short*)smem;          // [64][136] bf16
  unsigned*       wt = (unsigned*)(smem + 17408);      // [128][68] u32
  float*         wtf = (float*)(smem + 17408);         // [64][132] f32 (epilogue)
  const int rbase = blockIdx.x * 64;
#pragma unroll
  for (int it = 0; it < 8; ++it) {
    const int fidx = t + it * 256;
    const int row = fidx >> 5;
    const int c4  = fidx & 31;
    const int rg  = rbase + row;
    float4 v = (rg < N_) ? ((const float4*)x)[(size_t)rg * 32 + c4]
                         : make_float4(0.f, 0.f, 0.f, 0.f);
    *(uint2*)&xs[row * 136 + c4 * 4] =
        make_uint2(pack2bf(v.x, v.y), pack2bf(v.z, v.w));
  }
#pragma unroll
  for (int it = 0; it < 32; ++it) {
    const int idx = t + it * 256;
    const int n  = idx & 127;
    const int kk = idx >> 7;                // 0..63
    wt[n * 68 + kk] = pack2bf(W[(2 * kk) * 128 + n], W[(2 * kk + 1) * 128 + n]);
  }
  __syncthreads();
  const int wv = t >> 6;
  const int l  = t & 63;
  const int lr = l & 15;
  const int lg = l >> 4;
  f32x4 acc[8];
#pragma unroll
  for (int j = 0; j < 8; ++j) acc[j] = (f32x4){0.f, 0.f, 0.f, 0.f};
#pragma unroll
  for (int ks = 0; ks < 4; ++ks) {
    const short8 a = *(const short8*)&xs[(wv * 16 + lr) * 136 + ks * 32 + lg * 8];
#pragma unroll
    for (int j = 0; j < 8; ++j) {
      const short8 b = *(const short8*)&wt[(j * 16 + lr) * 68 + ks * 16 + lg * 4];
      acc[j] = __builtin_amdgcn_mfma_f32_16x16x32_bf16(a, b, acc[j], 0, 0, 0);
    }
  }
  __syncthreads();
#pragma unroll
  for (int j = 0; j < 8; ++j)
#pragma unroll
    for (int r = 0; r < 4; ++r)
      wtf[(wv * 16 + lg * 4 + r) * 132 + j * 16 + lr] = acc[j][r];
  __syncthreads();
#pragma unroll
  for (int it = 0; it < 16; ++it) {
    const int idx = t + it * 256;
    const int row = idx >> 6;
    const int c2  = idx & 63;
    const int rg  = rbase + row;
    if (rg < N_) {
      const float2 hv = *(const float2*)&wtf[row * 132 + c2 * 2];
      ((unsigned*)hbf)[(size_t)rg * 64 + c2] = pack2bf(hv.x, hv.y);
    }
  }
  {
    const int row = t & 63;
    const int q   = t >> 6;
    const int rg  = rbase + row;
    float ss = 0.f, sd = 0.f;
#pragma unroll
    for (int i = 0; i < 8; ++i) {
      const float4 hv = *(const float4*)&wtf[row * 132 + q * 32 + 4 * i];
      const float4 s4 = *(const float4*)&av_s[q * 32 + 4 * i];
      const float4 d4 = *(const float4*)&av_d[q * 32 + 4 * i];
      ss += hv.x * s4.x + hv.y * s4.y + hv.z * s4.z + hv.w * s4.w;
      sd += hv.x * d4.x + hv.y * d4.y + hv.z * d4.z + hv.w * d4.w;
    }
    if (rg < N_) { a_s[rg * 4 + q] = ss; a_d[rg * 4 + q] = sd; }
  }
}

// ---------------- GEMM2 (MFMA bf16): h2 = y1 @ W2 ; a_s2/a_d2 ------------
__global__ __launch_bounds__(256, 4) void k_gemm2(const unsigned* __restrict__ ybf,
    const float* __restrict__ W, const float* __restrict__ av_s,
    const float* __restrict__ av_d, unsigned short* __restrict__ hbf,
    float* __restrict__ a_s, float* __restrict__ a_d)
{
  __shared__ __align__(16) char smem[36864];
  unsigned short* xs = (unsigned short*)smem;          // [64][136] bf16 (y)
  unsigned*       wt = (unsigned*)(smem + 17408);      // [64][68] u32
  float*         wtf = (float*)(smem + 17408);         // [64][68] f32 (epilogue)
  float*          ps = (float*)(smem + 34816);         // [2][4][64] partials
  const int t = threadIdx.x;
  const int rbase = blockIdx.x * 64;
#pragma unroll
  for (int it = 0; it < 16; ++it) {
    const int idx = t + it * 256;
    const int row = idx >> 6;
    const int c2  = idx & 63;
    const int rg  = rbase + row;
    const unsigned u = (rg < N_) ? ybf[(size_t)rg * 64 + c2] : 0u;
    *(unsigned*)&xs[row * 136 + c2 * 2] = u;
  }
#pragma unroll
  for (int it = 0; it < 16; ++it) {
    const int idx = t + it * 256;
    const int n  = idx & 63;
    const int kk = idx >> 6;                // 0..63
    wt[n * 68 + kk] = pack2bf(W[(2 * kk) * 64 + n], W[(2 * kk + 1) * 64 + n]);
  }
  __syncthreads();
  const int wv = t >> 6;
  const int l  = t & 63;
  const int lr = l & 15;
  const int lg = l >> 4;
  f32x4 acc[4];
#pragma unroll
  for (int j = 0; j < 4; ++j) acc[j] = (f32x4){0.f, 0.f, 0.f, 0.f};
#pragma unroll
  for (int ks = 0; ks < 4; ++ks) {
    const short8 a = *(const short8*)&xs[(wv * 16 + lr) * 136 + ks * 32 + lg * 8];
#pragma unroll
    for (int j = 0; j < 4; ++j) {
      const short8 b = *(const short8*)&wt[(j * 16 + lr) * 68 + ks * 16 + lg * 4];
      acc[j] = __builtin_amdgcn_mfma_f32_16x16x32_bf16(a, b, acc[j], 0, 0, 0);
    }
  }
  __syncthreads();
#pragma unroll
  for (int j = 0; j < 4; ++j)
#pragma unroll
    for (int r = 0; r < 4; ++r)
      wtf[(wv * 16 + lg * 4 + r) * 68 + j * 16 + lr] = acc[j][r];
  __syncthreads();
#pragma unroll
  for (int it = 0; it < 8; ++it) {
    const int idx = t + it * 256;
    const int row = idx >> 5;
    const int c2  = idx & 31;
    const int rg  = rbase + row;
    if (rg < N_) {
      const float2 hv = *(const float2*)&wtf[row * 68 + c2 * 2];
      ((unsigned*)hbf)[(size_t)rg * 32 + c2] = pack2bf(hv.x, hv.y);
    }
  }
  {
    const int row = t & 63;
    const int g   = t >> 6;
    float ss = 0.f, sd = 0.f;
#pragma unroll
    for (int i = 0; i < 4; ++i) {
      const float4 hv = *(const float4*)&wtf[row * 68 + g * 16 + 4 * i];
      const float4 s4 = *(const float4*)&av_s[g * 16 + 4 * i];
      const float4 d4 = *(const float4*)&av_d[g * 16 + 4 * i];
      ss += hv.x * s4.x + hv.y * s4.y + hv.z * s4.z + hv.w * s4.w;
      sd += hv.x * d4.x + hv.y * d4.y + hv.z * d4.z + hv.w * d4.w;
    }
    ps[g * 64 + row] = ss;
    ps[256 + g * 64 + row] = sd;
  }
  __syncthreads();
  if (t < 64) {
    const int rg = rbase + t;
    if (rg < N_) {
      a_s[rg] = ps[t] + ps[64 + t] + ps[128 + t] + ps[192 + t];
      a_d[rg] = ps[256 + t] + ps[320 + t] + ps[384 + t] + ps[448 + t];
    }
  }
}

// ---------------- CSR build (scan/scatter/bucket) ----------------
__global__ __launch_bounds__(512) void k_scan(const int* __restrict__ gcount,
    int* __restrict__ goff, int* __restrict__ gcursor)
{
  __shared__ int sd[512];
  const int t = threadIdx.x;
  const int v = (t < NB_) ? gcount[t] : 0;
  sd[t] = v;
  __syncthreads();
  for (int off = 1; off < 512; off <<= 1) {
    const int add = (t >= off) ? sd[t - off] : 0;
    __syncthreads();
    sd[t] += add;
    __syncthreads();
  }
  if (t < NB_) { goff[t] = sd[t] - v; gcursor[t] = sd[t] - v; }
  if (t == 0) goff[NB_] = EP_;
}

__global__ __launch_bounds__(256) void k_scatter(const int* __restrict__ ei,
    int* __restrict__ gcursor, unsigned* __restrict__ eb1)
{
  __shared__ int nh[NB_];
  __shared__ int gb[NB_];
  const int t = threadIdx.x;
  for (int j = t; j < NB_; j += 256) nh[j] = 0;
  __syncthreads();
  const int beg = blockIdx.x * CHUNK_;
  const int end = min(beg + CHUNK_, EP_);
  for (int i = beg + t; i < end; i += 256) {
    const int d = (i < E_) ? ei[E_ + i] : (i - E_);
    atomicAdd(&nh[d >> 7], 1);
  }
  __syncthreads();
  for (int j = t; j < NB_; j += 256) {
    const int c = nh[j];
    gb[j] = c ? atomicAdd(&gcursor[j], c) : 0;
    nh[j] = 0;
  }
  __syncthreads();
  for (int i = beg + t; i < end; i += 256) {
    int s, d;
    if (i < E_) { s = ei[i]; d = ei[E_ + i]; } else { s = d = i - E_; }
    const int b = d >> 7;
    const int r = atomicAdd(&nh[b], 1);
    eb1[gb[b] + r] = ((unsigned)s << 16) | (unsigned)d;   // both < 65536
  }
}

__global__ __launch_bounds__(256) void k_bucket(const unsigned* __restrict__ eb1,
    const int* __restrict__ goff, int* __restrict__ rowptr,
    int* __restrict__ ebuf)
{
  __shared__ int h[128];
  __shared__ int off[129];
  __shared__ unsigned arrv[CAPB_];
  const int b = blockIdx.x;
  const int t = threadIdx.x;
  const int base = goff[b];
  const int cnt  = goff[b + 1] - base;
  if (t < 128) h[t] = 0;
  __syncthreads();
  const bool fits = (cnt <= CAPB_);
  for (int i = t; i < cnt; i += 256) {
    const unsigned v = eb1[base + i];
    if (fits) arrv[i] = v;
    atomicAdd(&h[(int)(v & 0xFFFFu) - (b << 7)], 1);
  }
  __syncthreads();
  if (t < 64) {
    const int a0 = h[2 * t], a1 = h[2 * t + 1];
    int s = a0 + a1;
#pragma unroll
    for (int m = 1; m < 64; m <<= 1) {
      const int u = __shfl_up(s, m);
      if (t >= m) s += u;
    }
    off[2 * t + 1] = s - a1;
    off[2 * t]     = s - a1 - a0;
    if (t == 63) off[128] = s;
  }
  __syncthreads();
  if (t < 128) {
    const int dst = (b << 7) + t;
    if (dst < N_) rowptr[dst] = base + off[t];
  }
  if (b == NB_ - 1 && t == 0) rowptr[N_] = EP_;
  if (t < 128) h[t] = 0;   // reuse as rank counters
  __syncthreads();
  for (int i = t; i < cnt; i += 256) {
    const unsigned v = fits ? arrv[i] : eb1[base + i];
    const int dlow = (int)(v & 0xFFFFu) - (b << 7);
    const int r = atomicAdd(&h[dlow], 1);
    ebuf[base + off[dlow] + r] = (int)(v >> 16);
  }
}

// ---------------- Layer-1 aggregation: 1 wave/dst, 2 edges/step ---------
// Lane loads 8B (4 channels); lanes 0-31 even edges, 32-63 odd edges.
// Halves serial steps + load instructions vs 4B/lane; merged shfl_xor(32).
__global__ __launch_bounds__(256, 4) void k_agg1(const int* __restrict__ rowptr,
    const int* __restrict__ ebuf, const float* __restrict__ a_s,
    const float* __restrict__ a_d, const unsigned short* __restrict__ hbf,
    const float* __restrict__ b1, unsigned* __restrict__ y)
{
  __shared__ uint2 pl[4][4 * 65];
  const int w = threadIdx.x >> 6;
  const int l = threadIdx.x & 63;
  const int d = blockIdx.x * 4 + w;
  const int base = rowptr[d];
  const int deg  = rowptr[d + 1] - base;
  const float4 ad = *(const float4*)&a_d[(size_t)d * 4];

  if (deg <= 64) {
    int   sreg = 0;
    float e0 = -1e30f, e1 = -1e30f, e2 = -1e30f, e3 = -1e30f;
    if (l < deg) {
      sreg = ebuf[base + l];
      const float4 as = *(const float4*)&a_s[(size_t)sreg * 4];
      e0 = as.x + ad.x; e0 = e0 > 0.f ? e0 : SLOPE * e0;
      e1 = as.y + ad.y; e1 = e1 > 0.f ? e1 : SLOPE * e1;
      e2 = as.z + ad.z; e2 = e2 > 0.f ? e2 : SLOPE * e2;
      e3 = as.w + ad.w; e3 = e3 > 0.f ? e3 : SLOPE * e3;
    }
    float mx0 = e0, mx1 = e1, mx2 = e2, mx3 = e3;
#pragma unroll
    for (int m = 32; m >= 1; m >>= 1) {
      mx0 = fmaxf(mx0, __shfl_xor(mx0, m));
      mx1 = fmaxf(mx1, __shfl_xor(mx1, m));
      mx2 = fmaxf(mx2, __shfl_xor(mx2, m));
      mx3 = fmaxf(mx3, __shfl_xor(mx3, m));
    }
    const float p0 = (l < deg) ? __expf(e0 - mx0) : 0.f;
    const float p1 = (l < deg) ? __expf(e1 - mx1) : 0.f;
    const float p2 = (l < deg) ? __expf(e2 - mx2) : 0.f;
    const float p3 = (l < deg) ? __expf(e3 - mx3) : 0.f;
    float sm0 = p0, sm1 = p1, sm2 = p2, sm3 = p3;
#pragma unroll
    for (int m = 32; m >= 1; m >>= 1) {
      sm0 += __shfl_xor(sm0, m);
      sm1 += __shfl_xor(sm1, m);
      sm2 += __shfl_xor(sm2, m);
      sm3 += __shfl_xor(sm3, m);
    }
    const float r0 = 1.f / (sm0 + 1e-16f);
    const float r1 = 1.f / (sm1 + 1e-16f);
    const float r2 = 1.f / (sm2 + 1e-16f);
    const float r3 = 1.f / (sm3 + 1e-16f);
    // zero-padded table (pad lanes: sreg=0, p=0)
    {
      const unsigned soff = (unsigned)sreg << 8;
      pl[w][0 * 65 + l] = make_uint2(soff, __float_as_uint(p0));
      pl[w][1 * 65 + l] = make_uint2(soff, __float_as_uint(p1));
      pl[w][2 * 65 + l] = make_uint2(soff, __float_as_uint(p2));
      pl[w][3 * 65 + l] = make_uint2(soff, __float_as_uint(p3));
    }
    const int eh = l >> 5;               // edge parity this lane handles
    const int cl = l & 31;               // channel-quad (chans 4cl..4cl+3)
    const int hsel = cl >> 3;            // head of those channels
    const unsigned coff = (unsigned)cl * 8u;
    const uint2* __restrict__ rp = &pl[w][hsel * 65];
    float acc0 = 0.f, acc1 = 0.f, acc2 = 0.f, acc3 = 0.f;
    const int niter = (deg + 15) >> 4;   // 16-edge batches (8 steps x 2)
    int bt = 0;
    for (; bt + 2 <= niter; bt += 2) {
      uint2 uA[8], uB[8];
      float pA[8], pB[8];
#pragma unroll
      for (int u = 0; u < 8; ++u) {
        const uint2 sp = rp[bt * 16 + 2 * u + eh];
        pA[u] = __uint_as_float(sp.y);
        uA[u] = *(const uint2*)((const char*)hbf + (sp.x + coff));
      }
#pragma unroll
      for (int u = 0; u < 8; ++u) {
        const uint2 sp = rp[bt * 16 + 16 + 2 * u + eh];
        pB[u] = __uint_as_float(sp.y);
        uB[u] = *(const uint2*)((const char*)hbf + (sp.x + coff));
      }
#pragma unroll
      for (int u = 0; u < 8; ++u) {
        acc0 = fmaf(pA[u], bf_lo(uA[u].x), acc0);
        acc1 = fmaf(pA[u], bf_hi(uA[u].x), acc1);
        acc2 = fmaf(pA[u], bf_lo(uA[u].y), acc2);
        acc3 = fmaf(pA[u], bf_hi(uA[u].y), acc3);
      }
#pragma unroll
      for (int u = 0; u < 8; ++u) {
        acc0 = fmaf(pB[u], bf_lo(uB[u].x), acc0);
        acc1 = fmaf(pB[u], bf_hi(uB[u].x), acc1);
        acc2 = fmaf(pB[u], bf_lo(uB[u].y), acc2);
        acc3 = fmaf(pB[u], bf_hi(uB[u].y), acc3);
      }
    }
    if (bt < niter) {
      uint2 uA[8];
      float pA[8];
#pragma unroll
      for (int u = 0; u < 8; ++u) {
        const uint2 sp = rp[bt * 16 + 2 * u + eh];
        pA[u] = __uint_as_float(sp.y);
        uA[u] = *(const uint2*)((const char*)hbf + (sp.x + coff));
      }
#pragma unroll
      for (int u = 0; u < 8; ++u) {
        acc0 = fmaf(pA[u], bf_lo(uA[u].x), acc0);
        acc1 = fmaf(pA[u], bf_hi(uA[u].x), acc1);
        acc2 = fmaf(pA[u], bf_lo(uA[u].y), acc2);
        acc3 = fmaf(pA[u], bf_hi(uA[u].y), acc3);
      }
    }
    // merge edge parities
    acc0 += __shfl_xor(acc0, 32);
    acc1 += __shfl_xor(acc1, 32);
    acc2 += __shfl_xor(acc2, 32);
    acc3 += __shfl_xor(acc3, 32);
    if (eh == 0) {
      const float rsel = hsel == 3 ? r3 : hsel == 2 ? r2 : hsel == 1 ? r1 : r0;
      const float4 bb = *(const float4*)&b1[4 * cl];
      float o0 = acc0 * rsel + bb.x;
      float o1 = acc1 * rsel + bb.y;
      float o2 = acc2 * rsel + bb.z;
      float o3 = acc3 * rsel + bb.w;
      o0 = o0 > 0.f ? o0 : expm1f(o0);
      o1 = o1 > 0.f ? o1 : expm1f(o1);
      o2 = o2 > 0.f ? o2 : expm1f(o2);
      o3 = o3 > 0.f ? o3 : expm1f(o3);
      *(uint2*)&y[(size_t)d * 64 + 2 * cl] =
          make_uint2(pack2bf(o0, o1), pack2bf(o2, o3));
    }
  } else {
    // ---- any-deg fallback (never taken for this graph, kept for safety) --
    const int hsel = l >> 4;
    float mx0 = -1e30f, mx1 = -1e30f, mx2 = -1e30f, mx3 = -1e30f;
    for (int i = l; i < deg; i += 64) {
      const int s = ebuf[base + i];
      const float4 as = *(const float4*)&a_s[(size_t)s * 4];
      float e0 = as.x + ad.x; e0 = e0 > 0.f ? e0 : SLOPE * e0;
      float e1 = as.y + ad.y; e1 = e1 > 0.f ? e1 : SLOPE * e1;
      float e2 = as.z + ad.z; e2 = e2 > 0.f ? e2 : SLOPE * e2;
      float e3 = as.w + ad.w; e3 = e3 > 0.f ? e3 : SLOPE * e3;
      mx0 = fmaxf(mx0, e0); mx1 = fmaxf(mx1, e1);
      mx2 = fmaxf(mx2, e2); mx3 = fmaxf(mx3, e3);
    }
#pragma unroll
    for (int m = 32; m >= 1; m >>= 1) {
      mx0 = fmaxf(mx0, __shfl_xor(mx0, m));
      mx1 = fmaxf(mx1, __shfl_xor(mx1, m));
      mx2 = fmaxf(mx2, __shfl_xor(mx2, m));
      mx3 = fmaxf(mx3, __shfl_xor(mx3, m));
    }
    float sm0 = 0.f, sm1 = 0.f, sm2 = 0.f, sm3 = 0.f;
    for (int i = l; i < deg; i += 64) {
      const int s = ebuf[base + i];
      const float4 as = *(const float4*)&a_s[(size_t)s * 4];
      float e0 = as.x + ad.x; e0 = e0 > 0.f ? e0 : SLOPE * e0;
      float e1 = as.y + ad.y; e1 = e1 > 0.f ? e1 : SLOPE * e1;
      float e2 = as.z + ad.z; e2 = e2 > 0.f ? e2 : SLOPE * e2;
      float e3 = as.w + ad.w; e3 = e3 > 0.f ? e3 : SLOPE * e3;
      sm0 += __expf(e0 - mx0); sm1 += __expf(e1 - mx1);
      sm2 += __expf(e2 - mx2); sm3 += __expf(e3 - mx3);
    }
#pragma unroll
    for (int m = 32; m >= 1; m >>= 1) {
      sm0 += __shfl_xor(sm0, m);
      sm1 += __shfl_xor(sm1, m);
      sm2 += __shfl_xor(sm2, m);
      sm3 += __shfl_xor(sm3, m);
    }
    const float r0 = 1.f / (sm0 + 1e-16f);
    const float r1 = 1.f / (sm1 + 1e-16f);
    const float r2 = 1.f / (sm2 + 1e-16f);
    const float r3 = 1.f / (sm3 + 1e-16f);
    const float mxs = hsel == 3 ? mx3 : hsel == 2 ? mx2 : hsel == 1 ? mx1 : mx0;
    float acc0 = 0.f, acc1 = 0.f;
    for (int i = 0; i < deg; ++i) {
      const int s = ebuf[base + i];
      const float4 as = *(const float4*)&a_s[(size_t)s * 4];
      float e0 = as.x + ad.x; e0 = e0 > 0.f ? e0 : SLOPE * e0;
      float e1 = as.y + ad.y; e1 = e1 > 0.f ? e1 : SLOPE * e1;
      float e2 = as.z + ad.z; e2 = e2 > 0.f ? e2 : SLOPE * e2;
      float e3 = as.w + ad.w; e3 = e3 > 0.f ? e3 : SLOPE * e3;
      const float es = hsel == 3 ? e3 : hsel == 2 ? e2 : hsel == 1 ? e1 : e0;
      const float pa = __expf(es - mxs);
      const unsigned uu = ((const unsigned*)(hbf + (size_t)s * 128))[l];
      acc0 = fmaf(pa, bf_lo(uu), acc0);
      acc1 = fmaf(pa, bf_hi(uu), acc1);
    }
    const float rsel = hsel == 3 ? r3 : hsel == 2 ? r2 : hsel == 1 ? r1 : r0;
    const float2 bb = *(const float2*)&b1[2 * l];
    float o0 = acc0 * rsel + bb.x;
    float o1 = acc1 * rsel + bb.y;
    o0 = o0 > 0.f ? o0 : expm1f(o0);
    o1 = o1 > 0.f ? o1 : expm1f(o1);
    y[(size_t)d * 64 + l] = pack2bf(o0, o1);
  }
}

// ---------------- Layer-2 aggregation: 1 wave/dst, 4 edges/step ---------
// Lane loads 8B (4 channels); 16 lanes per 128B row -> 4 edges/step.
// Merge shfl_xor(32) then shfl_xor(16); lanes 0-15 write float4.
__global__ __launch_bounds__(256, 4) void k_agg2(const int* __restrict__ rowptr,
    const int* __restrict__ ebuf, const float* __restrict__ a_s,
    const float* __restrict__ a_d, const unsigned short* __restrict__ hbf,
    const float* __restrict__ b2, float* __restrict__ out)
{
  __shared__ uint2 pl2[4][66];
  const int w = threadIdx.x >> 6;
  const int l = threadIdx.x & 63;
  const int d = blockIdx.x * 4 + w;
  const int base = rowptr[d];
  const int deg  = rowptr[d + 1] - base;
  const float ad = a_d[d];

  if (deg <= 64) {
    int   sreg = 0;
    float e = -1e30f;
    if (l < deg) {
      sreg = ebuf[base + l];
      e = a_s[sreg] + ad; e = e > 0.f ? e : SLOPE * e;
    }
    float mx = e;
#pragma unroll
    for (int m = 32; m >= 1; m >>= 1) mx = fmaxf(mx, __shfl_xor(mx, m));
    const float p = (l < deg) ? __expf(e - mx) : 0.f;
    float sm = p;
#pragma unroll
    for (int m = 32; m >= 1; m >>= 1) sm += __shfl_xor(sm, m);
    const float rv = 1.f / (sm + 1e-16f);
    pl2[w][l] = make_uint2((unsigned)(l < deg ? sreg : 0) << 7,
                           __float_as_uint(p));   // zero-padded
    const int eq = l >> 4;               // edge residue this lane handles
    const int cl = l & 15;               // channel-quad (chans 4cl..4cl+3)
    const unsigned coff = (unsigned)cl * 8u;
    const uint2* __restrict__ rp = &pl2[w][0];
    float acc0 = 0.f, acc1 = 0.f, acc2 = 0.f, acc3 = 0.f;
    const int niter = (deg + 31) >> 5;   // 32-edge batches (8 steps x 4)
    int bt = 0;
    for (; bt + 2 <= niter; bt += 2) {
      uint2 uA[8], uB[8];
      float pA[8], pB[8];
#pragma unroll
      for (int u = 0; u < 8; ++u) {
        const uint2 sp = rp[bt * 32 + 4 * u + eq];
        pA[u] = __uint_as_float(sp.y);
        uA[u] = *(const uint2*)((const char*)hbf + (sp.x + coff));
      }
#pragma unroll
      for (int u = 0; u < 8; ++u) {
        const uint2 sp = rp[bt * 32 + 32 + 4 * u + eq];
        pB[u] = __uint_as_float(sp.y);
        uB[u] = *(const uint2*)((const char*)hbf + (sp.x + coff));
      }
#pragma unroll
      for (int u = 0; u < 8; ++u) {
        acc0 = fmaf(pA[u], bf_lo(uA[u].x), acc0);
        acc1 = fmaf(pA[u], bf_hi(uA[u].x), acc1);
        acc2 = fmaf(pA[u], bf_lo(uA[u].y), acc2);
        acc3 = fmaf(pA[u], bf_hi(uA[u].y), acc3);
      }
#pragma unroll
      for (int u = 0; u < 8; ++u) {
        acc0 = fmaf(pB[u], bf_lo(uB[u].x), acc0);
        acc1 = fmaf(pB[u], bf_hi(uB[u].x), acc1);
        acc2 = fmaf(pB[u], bf_lo(uB[u].y), acc2);
        acc3 = fmaf(pB[u], bf_hi(uB[u].y), acc3);
      }
    }
    if (bt < niter) {
      uint2 uA[8];
      float pA[8];
#pragma unroll
      for (int u = 0; u < 8; ++u) {
        const uint2 sp = rp[bt * 32 + 4 * u + eq];
        pA[u] = __uint_as_float(sp.y);
        uA[u] = *(const uint2*)((const char*)hbf + (sp.x + coff));
      }
#pragma unroll
      for (int u = 0; u < 8; ++u) {
        acc0 = fmaf(pA[u], bf_lo(uA[u].x), acc0);
        acc1 = fmaf(pA[u], bf_hi(uA[u].x), acc1);
        acc2 = fmaf(pA[u], bf_lo(uA[u].y), acc2);
        acc3 = fmaf(pA[u], bf_hi(uA[u].y), acc3);
      }
    }
    acc0 += __shfl_xor(acc0, 32);
    acc1 += __shfl_xor(acc1, 32);
    acc2 += __shfl_xor(acc2, 32);
    acc3 += __shfl_xor(acc3, 32);
    acc0 += __shfl_xor(acc0, 16);
    acc1 += __shfl_xor(acc1, 16);
    acc2 += __shfl_xor(acc2, 16);
    acc3 += __shfl_xor(acc3, 16);
    if (eq == 0) {
      const float4 bb = *(const float4*)&b2[4 * cl];
      *(float4*)&out[(size_t)d * 64 + 4 * cl] =
          make_float4(acc0 * rv + bb.x, acc1 * rv + bb.y,
                      acc2 * rv + bb.z, acc3 * rv + bb.w);
    }
  } else {
    const int lh = l & 31;
    const bool hi = (l >= 32);
    float mx = -1e30f;
    for (int i = l; i < deg; i += 64) {
      const int s = ebuf[base + i];
      float e = a_s[s] + ad; e = e > 0.f ? e : SLOPE * e;
      mx = fmaxf(mx, e);
    }
#pragma unroll
    for (int m = 32; m >= 1; m >>= 1) mx = fmaxf(mx, __shfl_xor(mx, m));
    float sm = 0.f;
    for (int i = l; i < deg; i += 64) {
      const int s = ebuf[base + i];
      float e = a_s[s] + ad; e = e > 0.f ? e : SLOPE * e;
      sm += __expf(e - mx);
    }
#pragma unroll
    for (int m = 32; m >= 1; m >>= 1) sm += __shfl_xor(sm, m);
    const float rv = 1.f / (sm + 1e-16f);
    float acc0 = 0.f, acc1 = 0.f;
    for (int i = 0; i < deg; ++i) {
      const int s = ebuf[base + i];
      float e = a_s[s] + ad; e = e > 0.f ? e : SLOPE * e;
      const float pp = hi ? 0.f : __expf(e - mx);
      const unsigned uu = ((const unsigned*)(hbf + (size_t)s * 64))[lh];
      acc0 = fmaf(pp, bf_lo(uu), acc0);
      acc1 = fmaf(pp, bf_hi(uu), acc1);
    }
    acc0 += __shfl_xor(acc0, 32);
    acc1 += __shfl_xor(acc1, 32);
    if (!hi) {
      const int c0 = 2 * lh;
      const float2 bb = *(const float2*)&b2[c0];
      *(float2*)&out[(size_t)d * 64 + c0] =
          make_float2(acc0 * rv + bb.x, acc1 * rv + bb.y);
    }
  }
}

extern "C" void kernel_launch(void* const* d_in, const int* in_sizes, int n_in,
                              void* d_out, int out_size, void* d_ws, size_t ws_size,
                              hipStream_t stream) {
  const float* x     = (const float*)d_in[0];
  const int*   ei    = (const int*)d_in[1];
  const float* W1    = (const float*)d_in[2];
  const float* as1v  = (const float*)d_in[3];
  const float* ad1v  = (const float*)d_in[4];
  const float* b1    = (const float*)d_in[5];
  const float* W2    = (const float*)d_in[6];
  const float* as2v  = (const float*)d_in[7];
  const float* ad2v  = (const float*)d_in[8];
  const float* b2    = (const float*)d_in[9];
  float* out = (float*)d_out;

  char* ws = (char*)d_ws;
  unsigned short* h1 = (unsigned short*)(ws + OFF_H1);
  unsigned* y1       = (unsigned*)(ws + OFF_Y1);
  unsigned short* h2 = (unsigned short*)(ws + OFF_H2);
  float* a_s1 = (float*)(ws + OFF_AS1);
  float* a_d1 = (float*)(ws + OFF_AD1);
  float* a_s2 = (float*)(ws + OFF_AS2);
  float* a_d2 = (float*)(ws + OFF_AD2);
  int* rowptr = (int*)(ws + OFF_ROW);
  int* gcount = (int*)(ws + OFF_GC);
  int* goff   = (int*)(ws + OFF_GO);
  int* gcur   = (int*)(ws + OFF_GU);
  unsigned* eb1 = (unsigned*)(ws + OFF_EB1);
  int* ebuf   = (int*)(ws + OFF_EB);

  hipMemsetAsync(gcount, 0, (size_t)NB_ * 4, stream);

  k_g1h<<<NBLKG_ + NBLKA_, 256, 0, stream>>>(x, W1, as1v, ad1v, h1, a_s1, a_d1,
                                             ei, gcount);
  k_scan<<<1, 512, 0, stream>>>(gcount, goff, gcur);
  k_scatter<<<NBLKA_, 256, 0, stream>>>(ei, gcur, eb1);
  k_bucket<<<NB_, 256, 0, stream>>>(eb1, goff, rowptr, ebuf);
  k_agg1<<<N_ / 4, 256, 0, stream>>>(rowptr, ebuf, a_s1, a_d1, h1, b1, y1);
  k_gemm2<<<NBLKG_, 256, 0, stream>>>(y1, W2, as2v, ad2v, h2, a_s2, a_d2);
  k_agg2<<<N_ / 4, 256, 0, stream>>>(rowptr, ebuf, a_s2, a_d2, h2, b2, out);
}

// Round 14
// 145.408 us; speedup vs baseline: 1.1489x; 1.1489x over previous
//
#include <hip/hip_runtime.h>
#include <math.h>

namespace {
constexpr int N_   = 50000;
constexpr int E_   = 800000;
constexpr int EP_  = E_ + N_;   // edges + self loops = 850000
constexpr float SLOPE = 0.2f;

constexpr int NB_    = (N_ + 127) / 128;          // 391 coarse buckets (dst>>7)
constexpr int CHUNK_ = 8192;                      // edges per scatter block
constexpr int NBLKA_ = (EP_ + CHUNK_ - 1) / CHUNK_; // 104
constexpr int CAPB_  = 4096;                      // LDS capacity per bucket
constexpr int NBLKG_ = (N_ + 63) / 64;            // 782 gemm blocks (64 rows)

// workspace layout (bytes)
constexpr size_t OFF_H1  = 0;                                    // [N][128] bf16
constexpr size_t OFF_Y1  = OFF_H1  + (size_t)N_ * 128 * 2;       // [N][128] bf16
constexpr size_t OFF_H2  = OFF_Y1  + (size_t)N_ * 128 * 2;       // [N][64] bf16
constexpr size_t OFF_AS1 = OFF_H2  + (size_t)N_ * 64 * 2;        // [N][4]
constexpr size_t OFF_AD1 = OFF_AS1 + (size_t)N_ * 4 * 4;         // [N][4]
constexpr size_t OFF_AS2 = OFF_AD1 + (size_t)N_ * 4 * 4;         // [N]
constexpr size_t OFF_AD2 = OFF_AS2 + (size_t)N_ * 4;             // [N]
constexpr size_t OFF_ROW = OFF_AD2 + (size_t)N_ * 4;             // [N+1] int
constexpr size_t OFF_GC  = OFF_ROW + (((size_t)(N_ + 1) * 4 + 15) & ~(size_t)15); // [NB] int
constexpr size_t OFF_GO  = OFF_GC  + (((size_t)NB_ * 4 + 15) & ~(size_t)15);      // [NB+1] int
constexpr size_t OFF_GU  = OFF_GO  + (((size_t)(NB_ + 1) * 4 + 15) & ~(size_t)15);// [NB] int
constexpr size_t OFF_EB1 = OFF_GU  + (((size_t)NB_ * 4 + 15) & ~(size_t)15);      // [EP] u32 (src<<16|dst)
constexpr size_t OFF_EB  = OFF_EB1 + (size_t)EP_ * 4;            // [EP] int (src, dst-sorted)
}

typedef __attribute__((ext_vector_type(8))) short short8;
typedef __attribute__((ext_vector_type(4))) float f32x4;

__device__ __forceinline__ unsigned short f2bf(float x) {   // RNE
  unsigned u = __float_as_uint(x);
  return (unsigned short)((u + 0x7FFFu + ((u >> 16) & 1u)) >> 16);
}
__device__ __forceinline__ unsigned pack2bf(float a, float b) {
  return (unsigned)f2bf(a) | ((unsigned)f2bf(b) << 16);
}
__device__ __forceinline__ float bf_lo(unsigned u) { return __uint_as_float(u << 16); }
__device__ __forceinline__ float bf_hi(unsigned u) { return __uint_as_float(u & 0xFFFF0000u); }

// ------- Fused GEMM1 (MFMA bf16) + edge histogram -------------------------
__global__ __launch_bounds__(256, 3) void k_g1h(const float* __restrict__ x,
    const float* __restrict__ W, const float* __restrict__ av_s,
    const float* __restrict__ av_d, unsigned short* __restrict__ hbf,
    float* __restrict__ a_s, float* __restrict__ a_d,
    const int* __restrict__ ei, int* __restrict__ gcount)
{
  __shared__ __align__(16) char smem[52224];
  const int t = threadIdx.x;
  if (blockIdx.x >= NBLKG_) {
    int* nh = (int*)smem;
    for (int j = t; j < NB_; j += 256) nh[j] = 0;
    __syncthreads();
    const int beg = (blockIdx.x - NBLKG_) * CHUNK_;
    const int end = min(beg + CHUNK_, EP_);
    for (int i = beg + t; i < end; i += 256) {
      const int dd = (i < E_) ? ei[E_ + i] : (i - E_);
      atomicAdd(&nh[dd >> 7], 1);
    }
    __syncthreads();
    for (int j = t; j < NB_; j += 256)
      if (nh[j]) atomicAdd(&gcount[j], nh[j]);
    return;
  }
  unsigned short* xs = (unsigned short*)smem;          // [64][136] bf16
  unsigned*       wt = (unsigned*)(smem + 17408);      // [128][68] u32
  float*         wtf = (float*)(smem + 17408);         // [64][132] f32 (epilogue)
  const int rbase = blockIdx.x * 64;
#pragma unroll
  for (int it = 0; it < 8; ++it) {
    const int fidx = t + it * 256;
    const int row = fidx >> 5;
    const int c4  = fidx & 31;
    const int rg  = rbase + row;
    float4 v = (rg < N_) ? ((const float4*)x)[(size_t)rg * 32 + c4]
                         : make_float4(0.f, 0.f, 0.f, 0.f);
    *(uint2*)&xs[row * 136 + c4 * 4] =
        make_uint2(pack2bf(v.x, v.y), pack2bf(v.z, v.w));
  }
#pragma unroll
  for (int it = 0; it < 32; ++it) {
    const int idx = t + it * 256;
    const int n  = idx & 127;
    const int kk = idx >> 7;                // 0..63
    wt[n * 68 + kk] = pack2bf(W[(2 * kk) * 128 + n], W[(2 * kk + 1) * 128 + n]);
  }
  __syncthreads();
  const int wv = t >> 6;
  const int l  = t & 63;
  const int lr = l & 15;
  const int lg = l >> 4;
  f32x4 acc[8];
#pragma unroll
  for (int j = 0; j < 8; ++j) acc[j] = (f32x4){0.f, 0.f, 0.f, 0.f};
#pragma unroll
  for (int ks = 0; ks < 4; ++ks) {
    const short8 a = *(const short8*)&xs[(wv * 16 + lr) * 136 + ks * 32 + lg * 8];
#pragma unroll
    for (int j = 0; j < 8; ++j) {
      const short8 b = *(const short8*)&wt[(j * 16 + lr) * 68 + ks * 16 + lg * 4];
      acc[j] = __builtin_amdgcn_mfma_f32_16x16x32_bf16(a, b, acc[j], 0, 0, 0);
    }
  }
  __syncthreads();
#pragma unroll
  for (int j = 0; j < 8; ++j)
#pragma unroll
    for (int r = 0; r < 4; ++r)
      wtf[(wv * 16 + lg * 4 + r) * 132 + j * 16 + lr] = acc[j][r];
  __syncthreads();
  // h1 store — 4096 u32 = 64 rows x 64 u32 -> 16 iters
#pragma unroll
  for (int it = 0; it < 16; ++it) {
    const int idx = t + it * 256;
    const int row = idx >> 6;
    const int c2  = idx & 63;
    const int rg  = rbase + row;
    if (rg < N_) {
      const float2 hv = *(const float2*)&wtf[row * 132 + c2 * 2];
      ((unsigned*)hbf)[(size_t)rg * 64 + c2] = pack2bf(hv.x, hv.y);
    }
  }
  {
    const int row = t & 63;
    const int q   = t >> 6;
    const int rg  = rbase + row;
    float ss = 0.f, sd = 0.f;
#pragma unroll
    for (int i = 0; i < 8; ++i) {
      const float4 hv = *(const float4*)&wtf[row * 132 + q * 32 + 4 * i];
      const float4 s4 = *(const float4*)&av_s[q * 32 + 4 * i];
      const float4 d4 = *(const float4*)&av_d[q * 32 + 4 * i];
      ss += hv.x * s4.x + hv.y * s4.y + hv.z * s4.z + hv.w * s4.w;
      sd += hv.x * d4.x + hv.y * d4.y + hv.z * d4.z + hv.w * d4.w;
    }
    if (rg < N_) { a_s[rg * 4 + q] = ss; a_d[rg * 4 + q] = sd; }
  }
}

// ---------------- GEMM2 (MFMA bf16): h2 = y1 @ W2 ; a_s2/a_d2 ------------
__global__ __launch_bounds__(256, 4) void k_gemm2(const unsigned* __restrict__ ybf,
    const float* __restrict__ W, const float* __restrict__ av_s,
    const float* __restrict__ av_d, unsigned short* __restrict__ hbf,
    float* __restrict__ a_s, float* __restrict__ a_d)
{
  __shared__ __align__(16) char smem[36864];
  unsigned short* xs = (unsigned short*)smem;          // [64][136] bf16 (y)
  unsigned*       wt = (unsigned*)(smem + 17408);      // [64][68] u32
  float*         wtf = (float*)(smem + 17408);         // [64][68] f32 (epilogue)
  float*          ps = (float*)(smem + 34816);         // [2][4][64] partials
  const int t = threadIdx.x;
  const int rbase = blockIdx.x * 64;
#pragma unroll
  for (int it = 0; it < 16; ++it) {
    const int idx = t + it * 256;
    const int row = idx >> 6;
    const int c2  = idx & 63;
    const int rg  = rbase + row;
    const unsigned u = (rg < N_) ? ybf[(size_t)rg * 64 + c2] : 0u;
    *(unsigned*)&xs[row * 136 + c2 * 2] = u;
  }
#pragma unroll
  for (int it = 0; it < 16; ++it) {
    const int idx = t + it * 256;
    const int n  = idx & 63;
    const int kk = idx >> 6;                // 0..63
    wt[n * 68 + kk] = pack2bf(W[(2 * kk) * 64 + n], W[(2 * kk + 1) * 64 + n]);
  }
  __syncthreads();
  const int wv = t >> 6;
  const int l  = t & 63;
  const int lr = l & 15;
  const int lg = l >> 4;
  f32x4 acc[4];
#pragma unroll
  for (int j = 0; j < 4; ++j) acc[j] = (f32x4){0.f, 0.f, 0.f, 0.f};
#pragma unroll
  for (int ks = 0; ks < 4; ++ks) {
    const short8 a = *(const short8*)&xs[(wv * 16 + lr) * 136 + ks * 32 + lg * 8];
#pragma unroll
    for (int j = 0; j < 4; ++j) {
      const short8 b = *(const short8*)&wt[(j * 16 + lr) * 68 + ks * 16 + lg * 4];
      acc[j] = __builtin_amdgcn_mfma_f32_16x16x32_bf16(a, b, acc[j], 0, 0, 0);
    }
  }
  __syncthreads();
#pragma unroll
  for (int j = 0; j < 4; ++j)
#pragma unroll
    for (int r = 0; r < 4; ++r)
      wtf[(wv * 16 + lg * 4 + r) * 68 + j * 16 + lr] = acc[j][r];
  __syncthreads();
#pragma unroll
  for (int it = 0; it < 8; ++it) {
    const int idx = t + it * 256;
    const int row = idx >> 5;
    const int c2  = idx & 31;
    const int rg  = rbase + row;
    if (rg < N_) {
      const float2 hv = *(const float2*)&wtf[row * 68 + c2 * 2];
      ((unsigned*)hbf)[(size_t)rg * 32 + c2] = pack2bf(hv.x, hv.y);
    }
  }
  {
    const int row = t & 63;
    const int g   = t >> 6;
    float ss = 0.f, sd = 0.f;
#pragma unroll
    for (int i = 0; i < 4; ++i) {
      const float4 hv = *(const float4*)&wtf[row * 68 + g * 16 + 4 * i];
      const float4 s4 = *(const float4*)&av_s[g * 16 + 4 * i];
      const float4 d4 = *(const float4*)&av_d[g * 16 + 4 * i];
      ss += hv.x * s4.x + hv.y * s4.y + hv.z * s4.z + hv.w * s4.w;
      sd += hv.x * d4.x + hv.y * d4.y + hv.z * d4.z + hv.w * d4.w;
    }
    ps[g * 64 + row] = ss;
    ps[256 + g * 64 + row] = sd;
  }
  __syncthreads();
  if (t < 64) {
    const int rg = rbase + t;
    if (rg < N_) {
      a_s[rg] = ps[t] + ps[64 + t] + ps[128 + t] + ps[192 + t];
      a_d[rg] = ps[256 + t] + ps[320 + t] + ps[384 + t] + ps[448 + t];
    }
  }
}

// ---------------- CSR build (scan/scatter/bucket) ----------------
__global__ __launch_bounds__(512) void k_scan(const int* __restrict__ gcount,
    int* __restrict__ goff, int* __restrict__ gcursor)
{
  __shared__ int sd[512];
  const int t = threadIdx.x;
  const int v = (t < NB_) ? gcount[t] : 0;
  sd[t] = v;
  __syncthreads();
  for (int off = 1; off < 512; off <<= 1) {
    const int add = (t >= off) ? sd[t - off] : 0;
    __syncthreads();
    sd[t] += add;
    __syncthreads();
  }
  if (t < NB_) { goff[t] = sd[t] - v; gcursor[t] = sd[t] - v; }
  if (t == 0) goff[NB_] = EP_;
}

__global__ __launch_bounds__(256) void k_scatter(const int* __restrict__ ei,
    int* __restrict__ gcursor, unsigned* __restrict__ eb1)
{
  __shared__ int nh[NB_];
  __shared__ int gb[NB_];
  const int t = threadIdx.x;
  for (int j = t; j < NB_; j += 256) nh[j] = 0;
  __syncthreads();
  const int beg = blockIdx.x * CHUNK_;
  const int end = min(beg + CHUNK_, EP_);
  for (int i = beg + t; i < end; i += 256) {
    const int d = (i < E_) ? ei[E_ + i] : (i - E_);
    atomicAdd(&nh[d >> 7], 1);
  }
  __syncthreads();
  for (int j = t; j < NB_; j += 256) {
    const int c = nh[j];
    gb[j] = c ? atomicAdd(&gcursor[j], c) : 0;
    nh[j] = 0;
  }
  __syncthreads();
  for (int i = beg + t; i < end; i += 256) {
    int s, d;
    if (i < E_) { s = ei[i]; d = ei[E_ + i]; } else { s = d = i - E_; }
    const int b = d >> 7;
    const int r = atomicAdd(&nh[b], 1);
    eb1[gb[b] + r] = ((unsigned)s << 16) | (unsigned)d;   // both < 65536
  }
}

__global__ __launch_bounds__(256) void k_bucket(const unsigned* __restrict__ eb1,
    const int* __restrict__ goff, int* __restrict__ rowptr,
    int* __restrict__ ebuf)
{
  __shared__ int h[128];
  __shared__ int off[129];
  __shared__ unsigned arrv[CAPB_];
  const int b = blockIdx.x;
  const int t = threadIdx.x;
  const int base = goff[b];
  const int cnt  = goff[b + 1] - base;
  if (t < 128) h[t] = 0;
  __syncthreads();
  const bool fits = (cnt <= CAPB_);
  for (int i = t; i < cnt; i += 256) {
    const unsigned v = eb1[base + i];
    if (fits) arrv[i] = v;
    atomicAdd(&h[(int)(v & 0xFFFFu) - (b << 7)], 1);
  }
  __syncthreads();
  if (t < 64) {
    const int a0 = h[2 * t], a1 = h[2 * t + 1];
    int s = a0 + a1;
#pragma unroll
    for (int m = 1; m < 64; m <<= 1) {
      const int u = __shfl_up(s, m);
      if (t >= m) s += u;
    }
    off[2 * t + 1] = s - a1;
    off[2 * t]     = s - a1 - a0;
    if (t == 63) off[128] = s;
  }
  __syncthreads();
  if (t < 128) {
    const int dst = (b << 7) + t;
    if (dst < N_) rowptr[dst] = base + off[t];
  }
  if (b == NB_ - 1 && t == 0) rowptr[N_] = EP_;
  if (t < 128) h[t] = 0;   // reuse as rank counters
  __syncthreads();
  for (int i = t; i < cnt; i += 256) {
    const unsigned v = fits ? arrv[i] : eb1[base + i];
    const int dlow = (int)(v & 0xFFFFu) - (b << 7);
    const int r = atomicAdd(&h[dlow], 1);
    ebuf[base + off[dlow] + r] = (int)(v >> 16);
  }
}

// ---------------- Layer-1 aggregation: 1 wave/dst, bf16 h, 128 ch -------
// Best-known config (R10): 4B/lane, zero-padded (src_off,p) table, tail-free
// batch loop with 2 batches of 8 edges in flight, launch_bounds (256,4).
__global__ __launch_bounds__(256, 4) void k_agg1(const int* __restrict__ rowptr,
    const int* __restrict__ ebuf, const float* __restrict__ a_s,
    const float* __restrict__ a_d, const unsigned short* __restrict__ hbf,
    const float* __restrict__ b1, unsigned* __restrict__ y)
{
  __shared__ uint2 pl[4][4 * 65];
  const int w = threadIdx.x >> 6;
  const int l = threadIdx.x & 63;
  const int d = blockIdx.x * 4 + w;
  const int base = rowptr[d];
  const int deg  = rowptr[d + 1] - base;
  const float4 ad = *(const float4*)&a_d[(size_t)d * 4];
  const int hsel = l >> 4;
  const unsigned l4 = (unsigned)l * 4u;
  float acc0 = 0.f, acc1 = 0.f;
  float r0, r1, r2, r3;

  if (deg <= 64) {
    int   sreg = 0;
    float e0 = -1e30f, e1 = -1e30f, e2 = -1e30f, e3 = -1e30f;
    if (l < deg) {
      sreg = ebuf[base + l];
      const float4 as = *(const float4*)&a_s[(size_t)sreg * 4];
      e0 = as.x + ad.x; e0 = e0 > 0.f ? e0 : SLOPE * e0;
      e1 = as.y + ad.y; e1 = e1 > 0.f ? e1 : SLOPE * e1;
      e2 = as.z + ad.z; e2 = e2 > 0.f ? e2 : SLOPE * e2;
      e3 = as.w + ad.w; e3 = e3 > 0.f ? e3 : SLOPE * e3;
    }
    float mx0 = e0, mx1 = e1, mx2 = e2, mx3 = e3;
#pragma unroll
    for (int m = 32; m >= 1; m >>= 1) {
      mx0 = fmaxf(mx0, __shfl_xor(mx0, m));
      mx1 = fmaxf(mx1, __shfl_xor(mx1, m));
      mx2 = fmaxf(mx2, __shfl_xor(mx2, m));
      mx3 = fmaxf(mx3, __shfl_xor(mx3, m));
    }
    const float p0 = (l < deg) ? __expf(e0 - mx0) : 0.f;
    const float p1 = (l < deg) ? __expf(e1 - mx1) : 0.f;
    const float p2 = (l < deg) ? __expf(e2 - mx2) : 0.f;
    const float p3 = (l < deg) ? __expf(e3 - mx3) : 0.f;
    float sm0 = p0, sm1 = p1, sm2 = p2, sm3 = p3;
#pragma unroll
    for (int m = 32; m >= 1; m >>= 1) {
      sm0 += __shfl_xor(sm0, m);
      sm1 += __shfl_xor(sm1, m);
      sm2 += __shfl_xor(sm2, m);
      sm3 += __shfl_xor(sm3, m);
    }
    r0 = 1.f / (sm0 + 1e-16f);
    r1 = 1.f / (sm1 + 1e-16f);
    r2 = 1.f / (sm2 + 1e-16f);
    r3 = 1.f / (sm3 + 1e-16f);
    // zero-padded table: lanes l>=deg have sreg=0, p*=0
    {
      const unsigned soff = (unsigned)sreg << 8;
      pl[w][0 * 65 + l] = make_uint2(soff, __float_as_uint(p0));
      pl[w][1 * 65 + l] = make_uint2(soff, __float_as_uint(p1));
      pl[w][2 * 65 + l] = make_uint2(soff, __float_as_uint(p2));
      pl[w][3 * 65 + l] = make_uint2(soff, __float_as_uint(p3));
    }
    const uint2* __restrict__ rp = &pl[w][hsel * 65];
    const int niter = (deg + 7) >> 3;
    int it = 0;
    for (; it + 2 <= niter; it += 2) {
      unsigned uA[8], uB[8];
      float pA[8], pB[8];
#pragma unroll
      for (int u = 0; u < 8; ++u) {
        const uint2 sp = rp[it * 8 + u];
        pA[u] = __uint_as_float(sp.y);
        uA[u] = *(const unsigned*)((const char*)hbf + (sp.x + l4));
      }
#pragma unroll
      for (int u = 0; u < 8; ++u) {
        const uint2 sp = rp[it * 8 + 8 + u];
        pB[u] = __uint_as_float(sp.y);
        uB[u] = *(const unsigned*)((const char*)hbf + (sp.x + l4));
      }
#pragma unroll
      for (int u = 0; u < 8; ++u) {
        acc0 = fmaf(pA[u], bf_lo(uA[u]), acc0);
        acc1 = fmaf(pA[u], bf_hi(uA[u]), acc1);
      }
#pragma unroll
      for (int u = 0; u < 8; ++u) {
        acc0 = fmaf(pB[u], bf_lo(uB[u]), acc0);
        acc1 = fmaf(pB[u], bf_hi(uB[u]), acc1);
      }
    }
    if (it < niter) {
      unsigned uA[8];
      float pA[8];
#pragma unroll
      for (int u = 0; u < 8; ++u) {
        const uint2 sp = rp[it * 8 + u];
        pA[u] = __uint_as_float(sp.y);
        uA[u] = *(const unsigned*)((const char*)hbf + (sp.x + l4));
      }
#pragma unroll
      for (int u = 0; u < 8; ++u) {
        acc0 = fmaf(pA[u], bf_lo(uA[u]), acc0);
        acc1 = fmaf(pA[u], bf_hi(uA[u]), acc1);
      }
    }
  } else {
    // ---- any-deg fallback (never taken for this graph, kept for safety) --
    float mx0 = -1e30f, mx1 = -1e30f, mx2 = -1e30f, mx3 = -1e30f;
    for (int i = l; i < deg; i += 64) {
      const int s = ebuf[base + i];
      const float4 as = *(const float4*)&a_s[(size_t)s * 4];
      float e0 = as.x + ad.x; e0 = e0 > 0.f ? e0 : SLOPE * e0;
      float e1 = as.y + ad.y; e1 = e1 > 0.f ? e1 : SLOPE * e1;
      float e2 = as.z + ad.z; e2 = e2 > 0.f ? e2 : SLOPE * e2;
      float e3 = as.w + ad.w; e3 = e3 > 0.f ? e3 : SLOPE * e3;
      mx0 = fmaxf(mx0, e0); mx1 = fmaxf(mx1, e1);
      mx2 = fmaxf(mx2, e2); mx3 = fmaxf(mx3, e3);
    }
#pragma unroll
    for (int m = 32; m >= 1; m >>= 1) {
      mx0 = fmaxf(mx0, __shfl_xor(mx0, m));
      mx1 = fmaxf(mx1, __shfl_xor(mx1, m));
      mx2 = fmaxf(mx2, __shfl_xor(mx2, m));
      mx3 = fmaxf(mx3, __shfl_xor(mx3, m));
    }
    float sm0 = 0.f, sm1 = 0.f, sm2 = 0.f, sm3 = 0.f;
    for (int i = l; i < deg; i += 64) {
      const int s = ebuf[base + i];
      const float4 as = *(const float4*)&a_s[(size_t)s * 4];
      float e0 = as.x + ad.x; e0 = e0 > 0.f ? e0 : SLOPE * e0;
      float e1 = as.y + ad.y; e1 = e1 > 0.f ? e1 : SLOPE * e1;
      float e2 = as.z + ad.z; e2 = e2 > 0.f ? e2 : SLOPE * e2;
      float e3 = as.w + ad.w; e3 = e3 > 0.f ? e3 : SLOPE * e3;
      sm0 += __expf(e0 - mx0); sm1 += __expf(e1 - mx1);
      sm2 += __expf(e2 - mx2); sm3 += __expf(e3 - mx3);
    }
#pragma unroll
    for (int m = 32; m >= 1; m >>= 1) {
      sm0 += __shfl_xor(sm0, m);
      sm1 += __shfl_xor(sm1, m);
      sm2 += __shfl_xor(sm2, m);
      sm3 += __shfl_xor(sm3, m);
    }
    r0 = 1.f / (sm0 + 1e-16f);
    r1 = 1.f / (sm1 + 1e-16f);
    r2 = 1.f / (sm2 + 1e-16f);
    r3 = 1.f / (sm3 + 1e-16f);
    const float mxs = hsel == 3 ? mx3 : hsel == 2 ? mx2 : hsel == 1 ? mx1 : mx0;
    for (int i = 0; i < deg; ++i) {
      const int s = ebuf[base + i];
      const float4 as = *(const float4*)&a_s[(size_t)s * 4];
      float e0 = as.x + ad.x; e0 = e0 > 0.f ? e0 : SLOPE * e0;
      float e1 = as.y + ad.y; e1 = e1 > 0.f ? e1 : SLOPE * e1;
      float e2 = as.z + ad.z; e2 = e2 > 0.f ? e2 : SLOPE * e2;
      float e3 = as.w + ad.w; e3 = e3 > 0.f ? e3 : SLOPE * e3;
      const float es = hsel == 3 ? e3 : hsel == 2 ? e2 : hsel == 1 ? e1 : e0;
      const float pa = __expf(es - mxs);
      const unsigned uu = ((const unsigned*)(hbf + (size_t)s * 128))[l];
      acc0 = fmaf(pa, bf_lo(uu), acc0);
      acc1 = fmaf(pa, bf_hi(uu), acc1);
    }
  }
  const float rsel = hsel == 3 ? r3 : hsel == 2 ? r2 : hsel == 1 ? r1 : r0;
  const int c0 = 2 * l;
  const float2 bb = *(const float2*)&b1[c0];
  float o0 = acc0 * rsel + bb.x;
  float o1 = acc1 * rsel + bb.y;
  o0 = o0 > 0.f ? o0 : expm1f(o0);
  o1 = o1 > 0.f ? o1 : expm1f(o1);
  y[(size_t)d * 64 + l] = pack2bf(o0, o1);   // y1 stored bf16
}

// ---------------- Layer-2 aggregation: 1 wave/dst, bf16 h, 64 ch --------
__global__ __launch_bounds__(256, 4) void k_agg2(const int* __restrict__ rowptr,
    const int* __restrict__ ebuf, const float* __restrict__ a_s,
    const float* __restrict__ a_d, const unsigned short* __restrict__ hbf,
    const float* __restrict__ b2, float* __restrict__ out)
{
  __shared__ uint2 pl2[4][66];
  const int w = threadIdx.x >> 6;
  const int l = threadIdx.x & 63;
  const int lh = l & 31;
  const bool hi = (l >= 32);
  const int d = blockIdx.x * 4 + w;
  const int base = rowptr[d];
  const int deg  = rowptr[d + 1] - base;
  const float ad = a_d[d];
  const unsigned lh4 = (unsigned)lh * 4u;
  float acc0 = 0.f, acc1 = 0.f;
  float rv;

  if (deg <= 64) {
    int   sreg = 0;
    float e = -1e30f;
    if (l < deg) {
      sreg = ebuf[base + l];
      e = a_s[sreg] + ad; e = e > 0.f ? e : SLOPE * e;
    }
    float mx = e;
#pragma unroll
    for (int m = 32; m >= 1; m >>= 1) mx = fmaxf(mx, __shfl_xor(mx, m));
    const float p = (l < deg) ? __expf(e - mx) : 0.f;
    float sm = p;
#pragma unroll
    for (int m = 32; m >= 1; m >>= 1) sm += __shfl_xor(sm, m);
    rv = 1.f / (sm + 1e-16f);
    pl2[w][l] = make_uint2((unsigned)(l < deg ? sreg : 0) << 7,
                           __float_as_uint(p));   // zero-padded
    const uint2* __restrict__ rp = &pl2[w][hi ? 1 : 0];
    const int niter = (deg + 15) >> 4;   // batches of 16 edges (8 pairs)
    int it = 0;
    for (; it + 2 <= niter; it += 2) {
      unsigned uA[8], uB[8];
      float pA[8], pB[8];
#pragma unroll
      for (int u = 0; u < 8; ++u) {
        const uint2 sp = rp[it * 16 + 2 * u];
        pA[u] = __uint_as_float(sp.y);
        uA[u] = *(const unsigned*)((const char*)hbf + (sp.x + lh4));
      }
#pragma unroll
      for (int u = 0; u < 8; ++u) {
        const uint2 sp = rp[it * 16 + 16 + 2 * u];
        pB[u] = __uint_as_float(sp.y);
        uB[u] = *(const unsigned*)((const char*)hbf + (sp.x + lh4));
      }
#pragma unroll
      for (int u = 0; u < 8; ++u) {
        acc0 = fmaf(pA[u], bf_lo(uA[u]), acc0);
        acc1 = fmaf(pA[u], bf_hi(uA[u]), acc1);
      }
#pragma unroll
      for (int u = 0; u < 8; ++u) {
        acc0 = fmaf(pB[u], bf_lo(uB[u]), acc0);
        acc1 = fmaf(pB[u], bf_hi(uB[u]), acc1);
      }
    }
    if (it < niter) {
      unsigned uA[8];
      float pA[8];
#pragma unroll
      for (int u = 0; u < 8; ++u) {
        const uint2 sp = rp[it * 16 + 2 * u];
        pA[u] = __uint_as_float(sp.y);
        uA[u] = *(const unsigned*)((const char*)hbf + (sp.x + lh4));
      }
#pragma unroll
      for (int u = 0; u < 8; ++u) {
        acc0 = fmaf(pA[u], bf_lo(uA[u]), acc0);
        acc1 = fmaf(pA[u], bf_hi(uA[u]), acc1);
      }
    }
  } else {
    float mx = -1e30f;
    for (int i = l; i < deg; i += 64) {
      const int s = ebuf[base + i];
      float e = a_s[s] + ad; e = e > 0.f ? e : SLOPE * e;
      mx = fmaxf(mx, e);
    }
#pragma unroll
    for (int m = 32; m >= 1; m >>= 1) mx = fmaxf(mx, __shfl_xor(mx, m));
    float sm = 0.f;
    for (int i = l; i < deg; i += 64) {
      const int s = ebuf[base + i];
      float e = a_s[s] + ad; e = e > 0.f ? e : SLOPE * e;
      sm += __expf(e - mx);
    }
#pragma unroll
    for (int m = 32; m >= 1; m >>= 1) sm += __shfl_xor(sm, m);
    rv = 1.f / (sm + 1e-16f);
    for (int i = 0; i < deg; ++i) {
      const int s = ebuf[base + i];
      float e = a_s[s] + ad; e = e > 0.f ? e : SLOPE * e;
      const float pp = hi ? 0.f : __expf(e - mx);
      const unsigned uu = ((const unsigned*)(hbf + (size_t)s * 64))[lh];
      acc0 = fmaf(pp, bf_lo(uu), acc0);
      acc1 = fmaf(pp, bf_hi(uu), acc1);
    }
  }
  acc0 += __shfl_xor(acc0, 32);
  acc1 += __shfl_xor(acc1, 32);
  if (!hi) {
    const int c0 = 2 * lh;
    const float2 bb = *(const float2*)&b2[c0];
    *(float2*)&out[(size_t)d * 64 + c0] =
        make_float2(acc0 * rv + bb.x, acc1 * rv + bb.y);
  }
}

extern "C" void kernel_launch(void* const* d_in, const int* in_sizes, int n_in,
                              void* d_out, int out_size, void* d_ws, size_t ws_size,
                              hipStream_t stream) {
  const float* x     = (const float*)d_in[0];
  const int*   ei    = (const int*)d_in[1];
  const float* W1    = (const float*)d_in[2];
  const float* as1v  = (const float*)d_in[3];
  const float* ad1v  = (const float*)d_in[4];
  const float* b1    = (const float*)d_in[5];
  const float* W2    = (const float*)d_in[6];
  const float* as2v  = (const float*)d_in[7];
  const float* ad2v  = (const float*)d_in[8];
  const float* b2    = (const float*)d_in[9];
  float* out = (float*)d_out;

  char* ws = (char*)d_ws;
  unsigned short* h1 = (unsigned short*)(ws + OFF_H1);
  unsigned* y1       = (unsigned*)(ws + OFF_Y1);
  unsigned short* h2 = (unsigned short*)(ws + OFF_H2);
  float* a_s1 = (float*)(ws + OFF_AS1);
  float* a_d1 = (float*)(ws + OFF_AD1);
  float* a_s2 = (float*)(ws + OFF_AS2);
  float* a_d2 = (float*)(ws + OFF_AD2);
  int* rowptr = (int*)(ws + OFF_ROW);
  int* gcount = (int*)(ws + OFF_GC);
  int* goff   = (int*)(ws + OFF_GO);
  int* gcur   = (int*)(ws + OFF_GU);
  unsigned* eb1 = (unsigned*)(ws + OFF_EB1);
  int* ebuf   = (int*)(ws + OFF_EB);

  hipMemsetAsync(gcount, 0, (size_t)NB_ * 4, stream);

  k_g1h<<<NBLKG_ + NBLKA_, 256, 0, stream>>>(x, W1, as1v, ad1v, h1, a_s1, a_d1,
                                             ei, gcount);
  k_scan<<<1, 512, 0, stream>>>(gcount, goff, gcur);
  k_scatter<<<NBLKA_, 256, 0, stream>>>(ei, gcur, eb1);
  k_bucket<<<NB_, 256, 0, stream>>>(eb1, goff, rowptr, ebuf);
  k_agg1<<<N_ / 4, 256, 0, stream>>>(rowptr, ebuf, a_s1, a_d1, h1, b1, y1);
  k_gemm2<<<NBLKG_, 256, 0, stream>>>(y1, W2, as2v, ad2v, h2, a_s2, a_d2);
  k_agg2<<<N_ / 4, 256, 0, stream>>>(rowptr, ebuf, a_s2, a_d2, h2, b2, out);
}